// Round 16
// baseline (926.164 us; speedup 1.0000x reference)
//
#include <hip/hip_runtime.h>
#include <hip/hip_bf16.h>

typedef __hip_bfloat16 bf16;
typedef __bf16 bf16x8 __attribute__((ext_vector_type(8)));
typedef float f32x4 __attribute__((ext_vector_type(4)));
typedef unsigned short u16;
typedef unsigned int u32;

#define SEQ 512
#define DMODEL 1024
#define FFDIM 4096
#define NHEAD 16
#define HDIM 64
#define NB 4
#define NLAYER 8

#define SBAR() asm volatile("s_barrier" ::: "memory")

__device__ __forceinline__ u16 f2bu(float f) {
    union { bf16 h; u16 u; } c; c.h = __float2bfloat16(f); return c.u;
}
__device__ __forceinline__ float bu2f(u16 u) {
    union { u32 i; float f; } c; c.i = ((u32)u) << 16; return c.f;
}

// async global->LDS, 16B per lane. LDS dest must be linear in lane order.
__device__ __forceinline__ void gload16(const bf16* g, bf16* l) {
    __builtin_amdgcn_global_load_lds(
        (const __attribute__((address_space(1))) unsigned int*)g,
        (__attribute__((address_space(3))) unsigned int*)l,
        16, 0, 0);
}

// ---------------------------------------------------------------------------
// Deep-pipelined NT GEMM core, 3-buffer LDS ring: 256x128 tile, BK=64,
// 512 threads (8 waves 2Mx4N). stage(t+2) issues into the FREE ring slot at
// iteration start (overlaps MFMA); counted vmcnt(6) waits only tile t+1's
// loads; ONE barrier per K-tile. A: row-major global w/ st_16x32 swizzle via
// inverse-swizzled source. B: tiled global layout (swizzle pre-baked).
// ---------------------------------------------------------------------------
__device__ __forceinline__ void gemm_pipe(
    const bf16* __restrict__ A, int lda,
    const bf16* __restrict__ Bt,       // tiled B: + t*8192 per K-tile
    int nkt,
    f32x4 (&acc)[8][2],
    char* lA, char* lB)                // lA: 3 x 32KB, lB: 3 x 16KB
{
    const int tid = threadIdx.x;
    const int lane = tid & 63;
    const int wave = tid >> 6;
    const int wr = wave >> 2, wc = wave & 3;
    const int l15 = lane & 15, l4 = lane >> 4;

    auto stage = [&](int c, int t) {
        const bf16* Ak = A + t * 64;
        bf16* dA = (bf16*)(lA + c * 32768);
        bf16* dB = (bf16*)(lB + c * 16384);
#pragma unroll
        for (int it = 0; it < 4; ++it) {
            const int e = (it * 512 + tid) * 8;
            const int r = e >> 6;
            const int cb = (e & 63) * 2;
            const int sc = (cb ^ (((r >> 2) & 1) << 5)) >> 1;
            gload16(Ak + (long)r * lda + sc, dA + e);
        }
        const bf16* Bk = Bt + (long)t * 8192;
#pragma unroll
        for (int it = 0; it < 2; ++it) {
            const int e = (it * 512 + tid) * 8;
            gload16(Bk + e, dB + e);
        }
    };

    stage(0, 0);
    stage(1, 1);
    asm volatile("s_waitcnt vmcnt(6)" ::: "memory");   // tile 0 resident
    SBAR();

    for (int t = 0; t < nkt; ++t) {
        const int cur = t % 3;
        // issue next-next tile into the free ring slot; flies under MFMA.
        if (t + 2 < nkt) stage((t + 2) % 3, t + 2);

        const char* bA = lA + cur * 32768;
        const char* bB = lB + cur * 16384;

        bf16x8 bf_[2][2];
#pragma unroll
        for (int fn = 0; fn < 2; ++fn)
#pragma unroll
            for (int ks = 0; ks < 2; ++ks) {
                const int row = wc * 32 + fn * 16 + l15;
                int byte = row * 128 + (ks * 32 + l4 * 8) * 2;
                byte ^= ((row >> 2) & 1) << 5;
                bf_[fn][ks] = *(const bf16x8*)(bB + byte);
            }
#pragma unroll
        for (int q = 0; q < 4; ++q) {
            bf16x8 af[2][2];
#pragma unroll
            for (int i = 0; i < 2; ++i)
#pragma unroll
                for (int ks = 0; ks < 2; ++ks) {
                    const int row = wr * 128 + (q * 2 + i) * 16 + l15;
                    int byte = row * 128 + (ks * 32 + l4 * 8) * 2;
                    byte ^= ((row >> 2) & 1) << 5;
                    af[i][ks] = *(const bf16x8*)(bA + byte);
                }
            __builtin_amdgcn_s_setprio(1);
#pragma unroll
            for (int i = 0; i < 2; ++i)
#pragma unroll
                for (int fn = 0; fn < 2; ++fn)
#pragma unroll
                    for (int ks = 0; ks < 2; ++ks)
                        acc[q * 2 + i][fn] = __builtin_amdgcn_mfma_f32_16x16x32_bf16(
                            af[i][ks], bf_[fn][ks], acc[q * 2 + i][fn], 0, 0, 0);
            __builtin_amdgcn_s_setprio(0);
        }
        // wait tile t+1 (oldest 6 outstanding); t+2's 6 stay in flight
        if (t + 2 < nkt) {
            asm volatile("s_waitcnt vmcnt(6)" ::: "memory");
        } else if (t + 1 < nkt) {
            asm volatile("s_waitcnt vmcnt(0)" ::: "memory");
        }
        SBAR();   // tile t+1 visible to all; all waves past buf[cur] reads
    }
}

// ---------------------------------------------------------------------------
// LayerNorm: in (fp32, row of 1024) -> out bf16; optional passthrough copy.
// ---------------------------------------------------------------------------
__global__ __launch_bounds__(256) void k_ln(const float* __restrict__ h,
                                            const float* __restrict__ w,
                                            const float* __restrict__ bp,
                                            bf16* __restrict__ out,
                                            float* __restrict__ hcopy)
{
    const int row = blockIdx.x;
    const int tid = threadIdx.x;
    const float4 x = ((const float4*)(h + (long)row * DMODEL))[tid];
    if (hcopy) ((float4*)(hcopy + (long)row * DMODEL))[tid] = x;
    float s  = x.x + x.y + x.z + x.w;
    float s2 = x.x * x.x + x.y * x.y + x.z * x.z + x.w * x.w;
#pragma unroll
    for (int off = 32; off; off >>= 1) { s += __shfl_xor(s, off); s2 += __shfl_xor(s2, off); }
    __shared__ float rs[4], rs2[4];
    const int wave = tid >> 6;
    if ((tid & 63) == 0) { rs[wave] = s; rs2[wave] = s2; }
    __syncthreads();
    const float S1 = rs[0] + rs[1] + rs[2] + rs[3];
    const float S2 = rs2[0] + rs2[1] + rs2[2] + rs2[3];
    const float mean = S1 * (1.0f / DMODEL);
    const float var  = S2 * (1.0f / DMODEL) - mean * mean;
    const float rstd = rsqrtf(var + 1e-5f);
    const float4 wv = ((const float4*)w)[tid];
    const float4 bv = ((const float4*)bp)[tid];
    uint2 o;
    o.x = (u32)f2bu((x.x - mean) * rstd * wv.x + bv.x) |
          ((u32)f2bu((x.y - mean) * rstd * wv.y + bv.y) << 16);
    o.y = (u32)f2bu((x.z - mean) * rstd * wv.z + bv.z) |
          ((u32)f2bu((x.w - mean) * rstd * wv.w + bv.w) << 16);
    ((uint2*)(out + (long)row * DMODEL))[tid] = o;
}

// ---------------------------------------------------------------------------
// Weight -> swizzled-tile converter, v2: 128(k) x 256(n) region per block.
// Phase-1 reads: 1KB contiguous per row. Phase-2: emits 4 tiles (2 panels x
// 2 K-tiles); ki-inner ordering makes 32KB sequential write runs.
// Blob layout identical to v1 (verified): element e of tile = 
//   W[kt*64 + ((e&63) ^ (((e>>6)>>2 & 1)<<4))][n0 + (e>>6)].
// grid: NLAYER * 256 blocks (128 w1-regions + 128 w2-regions per layer).
// ---------------------------------------------------------------------------
__global__ __launch_bounds__(256) void k_tilew2(const float* __restrict__ w1,
                                                const float* __restrict__ w2,
                                                bf16* __restrict__ w1t,
                                                bf16* __restrict__ w2t)
{
    __shared__ u16 t[128][264];        // [k][n], padded (stride 132 dwords)
    int bid = blockIdx.x;
    const int l = bid >> 8;
    bid &= 255;
    const long lofs = (long)l * DMODEL * FFDIM;
    const float* src; bf16* dstb; int ldsrc, pkt, pbase, kbase;
    if (bid < 128) {
        // w1 [1024][4096]: kb = bid>>4 (0..7), nb = bid&15 (0..15)
        const int kb = bid >> 4, nb = bid & 15;
        src = w1 + lofs + (long)(kb * 128) * FFDIM + nb * 256;
        ldsrc = FFDIM;
        dstb = w1t + lofs; pkt = 16; pbase = nb * 2; kbase = kb * 2;
    } else {
        bid -= 128;
        // w2 [4096][1024]: kb = bid>>2 (0..31), nb = bid&3 (0..3)
        const int kb = bid >> 2, nb = bid & 3;
        src = w2 + lofs + (long)(kb * 128) * DMODEL + nb * 256;
        ldsrc = DMODEL;
        dstb = w2t + lofs; pkt = 64; pbase = nb * 2; kbase = kb * 2;
    }
    const int tid = threadIdx.x;
    // phase 1: 4 rows/iter, 64 lanes x float4 = 1KB per row
    const int n4 = (tid & 63) * 4;
    const int kr = tid >> 6;           // 0..3
#pragma unroll
    for (int j = 0; j < 32; ++j) {
        const int k = j * 4 + kr;
        const float4 v = *(const float4*)(src + (long)k * ldsrc + n4);
        t[k][n4]     = f2bu(v.x);
        t[k][n4 + 1] = f2bu(v.y);
        t[k][n4 + 2] = f2bu(v.z);
        t[k][n4 + 3] = f2bu(v.w);
    }
    __syncthreads();
    // phase 2: emit 4 tiles; ki inner so writes are 32KB sequential runs
#pragma unroll
    for (int pi = 0; pi < 2; ++pi)
#pragma unroll
        for (int ki = 0; ki < 2; ++ki) {
            bf16* dst = dstb + ((long)(pbase + pi) * pkt + (kbase + ki)) * 8192;
#pragma unroll
            for (int it = 0; it < 4; ++it) {
                const int e0 = it * 2048 + tid * 8;
                const int r = e0 >> 6;                  // n within tile
                const int c = e0 & 63;                  // k-group base
                const int ksw = c ^ (((r >> 2) & 1) << 4);
                u16 v[8];
#pragma unroll
                for (int m = 0; m < 8; ++m) v[m] = t[ki * 64 + ksw + m][pi * 128 + r];
                uint4 o;
                o.x = (u32)v[0] | ((u32)v[1] << 16);
                o.y = (u32)v[2] | ((u32)v[3] << 16);
                o.z = (u32)v[4] | ((u32)v[5] << 16);
                o.w = (u32)v[6] | ((u32)v[7] << 16);
                *(uint4*)(dst + e0) = o;
            }
        }
}

// ---------------------------------------------------------------------------
// Fused QKV + flash attention. grid (SEQ/128=4, B*H=64), 256 threads (4 waves,
// 32 q-rows each). Per block: stage Wq/Wk/Wv (fp32->bf16) + q-tile y-rows;
// project Q once; per kv-tile generate K,V via MFMA (bias fused, V stored
// transposed in LDS) then QK^T -> online softmax -> PV. h += O/l.
// ---------------------------------------------------------------------------
__global__ __launch_bounds__(256) void k_attn(const bf16* __restrict__ y,
                                              const float* __restrict__ qwl,
                                              const float* __restrict__ kwl,
                                              const float* __restrict__ vwl,
                                              const float* __restrict__ qb,
                                              const float* __restrict__ kb,
                                              const float* __restrict__ vb,
                                              float* __restrict__ h)
{
    __shared__ __align__(16) char lmem[65536];
    bf16* lY  = (bf16*)lmem;            // 16KB: y staging (A-swizzled)
    char* lQ  = lmem + 16384;           // 16KB: Q scatter; later per-wave P
    char* lK  = lmem + 32768;           // 8KB: Wq temp, then K tile
    char* lV  = lmem + 40960;           // 8KB: V tile (transposed)
    char* lWk = lmem + 49152;           // 8KB
    char* lWv = lmem + 57344;           // 8KB

    const int tid = threadIdx.x;
    const int lane = tid & 63, wave = tid >> 6;
    const int l15 = lane & 15, l4 = lane >> 4;
    const int z = blockIdx.y, b = z >> 4, hd = z & 15;
    const int q0 = blockIdx.x * 128;

    // stage Wq->lK(temp), Wk->lWk, Wv->lWv : fp32->bf16 + row swizzle
    {
        const float* s0 = qwl + (long)hd * HDIM * HDIM;
        const float* s1 = kwl + (long)hd * HDIM * HDIM;
        const float* s2 = vwl + (long)hd * HDIM * HDIM;
#pragma unroll
        for (int it = 0; it < 4; ++it) {
            const int f = (it * 256 + tid) * 4;
            const int row = f >> 6;
            const int byte = (f << 1) ^ ((row & 7) << 4);
            float4 v = *(const float4*)(s0 + f);
            uint2 o;
            o.x = (u32)f2bu(v.x) | ((u32)f2bu(v.y) << 16);
            o.y = (u32)f2bu(v.z) | ((u32)f2bu(v.w) << 16);
            *(uint2*)(lK + byte) = o;
            v = *(const float4*)(s1 + f);
            o.x = (u32)f2bu(v.x) | ((u32)f2bu(v.y) << 16);
            o.y = (u32)f2bu(v.z) | ((u32)f2bu(v.w) << 16);
            *(uint2*)(lWk + byte) = o;
            v = *(const float4*)(s2 + f);
            o.x = (u32)f2bu(v.x) | ((u32)f2bu(v.y) << 16);
            o.y = (u32)f2bu(v.z) | ((u32)f2bu(v.w) << 16);
            *(uint2*)(lWv + byte) = o;
        }
    }
    // stage y_q (128 rows) -> lY with inverse-swizzled source
    const bf16* Yq = y + ((long)b * SEQ + q0) * DMODEL + hd * HDIM;
#pragma unroll
    for (int it = 0; it < 4; ++it) {
        const int e = (it * 256 + tid) * 8;
        const int r = e >> 6;
        const int cb = (e & 63) * 2;
        const int sc = (cb ^ (((r >> 2) & 1) << 5)) >> 1;
        gload16(Yq + (long)r * DMODEL + sc, lY + e);
    }
    __syncthreads();

    // Q projection: per wave 32 rows; scatter to lQ (C-layout, row-swizzled)
    {
        f32x4 qacc[2][4] = {};
#pragma unroll
        for (int ks = 0; ks < 2; ++ks) {
            bf16x8 af[2];
#pragma unroll
            for (int fm = 0; fm < 2; ++fm) {
                const int row = wave * 32 + fm * 16 + l15;
                int byte = row * 128 + (ks * 32 + l4 * 8) * 2;
                byte ^= ((row >> 2) & 1) << 5;
                af[fm] = *(const bf16x8*)((char*)lY + byte);
            }
#pragma unroll
            for (int fn = 0; fn < 4; ++fn) {
                const int wrow = fn * 16 + l15;
                int wbyte = (wrow << 7) + ((ks * 32 + l4 * 8) << 1);
                wbyte ^= (wrow & 7) << 4;
                const bf16x8 wf = *(const bf16x8*)(lK + wbyte);
#pragma unroll
                for (int fm = 0; fm < 2; ++fm)
                    qacc[fm][fn] = __builtin_amdgcn_mfma_f32_16x16x32_bf16(
                        af[fm], wf, qacc[fm][fn], 0, 0, 0);
            }
        }
#pragma unroll
        for (int fm = 0; fm < 2; ++fm)
#pragma unroll
            for (int fn = 0; fn < 4; ++fn) {
                const int e = fn * 16 + l15;
                const float bias = qb[hd * HDIM + e];
#pragma unroll
                for (int r = 0; r < 4; ++r) {
                    const int row = wave * 32 + fm * 16 + l4 * 4 + r;
                    const int byte = ((row << 7) + (e << 1)) ^ ((row & 7) << 4);
                    *(u16*)(lQ + byte) = f2bu((qacc[fm][fn][r] + bias) * 0.125f);
                }
            }
    }
    __syncthreads();

    // qa readback (A-layout)
    bf16x8 qa[2][2];
#pragma unroll
    for (int fm = 0; fm < 2; ++fm)
#pragma unroll
        for (int ks = 0; ks < 2; ++ks) {
            const int row = wave * 32 + fm * 16 + l15;
            int byte = (row << 7) + ((ks * 32 + l4 * 8) << 1);
            byte ^= (row & 7) << 4;
            qa[fm][ks] = *(const bf16x8*)(lQ + byte);
        }

    char* lP = lQ + wave * 4096;   // wave-private 32x64 P (aliases own Q rows)

    f32x4 O[2][4] = {};
    float mrun[2][4], lrun[2][4];
#pragma unroll
    for (int fm = 0; fm < 2; ++fm)
#pragma unroll
        for (int r = 0; r < 4; ++r) { mrun[fm][r] = -1e30f; lrun[fm][r] = 0.0f; }

    for (int kv = 0; kv < SEQ / 64; ++kv) {
        __syncthreads();   // prior tile's lY/lK/lV readers done
        const bf16* Ykv = y + ((long)b * SEQ + kv * 64) * DMODEL + hd * HDIM;
#pragma unroll
        for (int it = 0; it < 2; ++it) {
            const int e = (it * 256 + tid) * 8;
            const int r = e >> 6;
            const int cb = (e & 63) * 2;
            const int sc = (cb ^ (((r >> 2) & 1) << 5)) >> 1;
            gload16(Ykv + (long)r * DMODEL + sc, lY + e);
        }
        __syncthreads();   // y_kv ready (vmcnt drained)

        // K,V generation: wave owns keys [wave*16, wave*16+16)
        {
            f32x4 kacc[4] = {}, vacc[4] = {};
#pragma unroll
            for (int ks = 0; ks < 2; ++ks) {
                const int yrow = wave * 16 + l15;
                int ybyte = yrow * 128 + (ks * 32 + l4 * 8) * 2;
                ybyte ^= ((yrow >> 2) & 1) << 5;
                const bf16x8 ay = *(const bf16x8*)((char*)lY + ybyte);
#pragma unroll
                for (int fn = 0; fn < 4; ++fn) {
                    const int wrow = fn * 16 + l15;
                    int wbyte = (wrow << 7) + ((ks * 32 + l4 * 8) << 1);
                    wbyte ^= (wrow & 7) << 4;
                    kacc[fn] = __builtin_amdgcn_mfma_f32_16x16x32_bf16(
                        ay, *(const bf16x8*)(lWk + wbyte), kacc[fn], 0, 0, 0);
                    vacc[fn] = __builtin_amdgcn_mfma_f32_16x16x32_bf16(
                        ay, *(const bf16x8*)(lWv + wbyte), vacc[fn], 0, 0, 0);
                }
            }
#pragma unroll
            for (int fn = 0; fn < 4; ++fn) {
                const int e = fn * 16 + l15;
                const float kbv = kb[hd * HDIM + e];
                const float vbv = vb[hd * HDIM + e];
#pragma unroll
                for (int r = 0; r < 4; ++r) {
                    const int key = wave * 16 + l4 * 4 + r;
                    const int kbyte = ((key << 7) + (e << 1)) ^ ((key & 7) << 4);
                    *(u16*)(lK + kbyte) = f2bu(kacc[fn][r] + kbv);
                    const int vbyte = ((e << 7) + (key << 1)) ^ ((e & 7) << 4);
                    *(u16*)(lV + vbyte) = f2bu(vacc[fn][r] + vbv);
                }
            }
        }
        __syncthreads();   // K/V tiles ready

        // QK^T
        f32x4 sa[2][4];
#pragma unroll
        for (int fm = 0; fm < 2; ++fm)
#pragma unroll
            for (int fn = 0; fn < 4; ++fn) sa[fm][fn] = (f32x4){0.f, 0.f, 0.f, 0.f};
#pragma unroll
        for (int ks = 0; ks < 2; ++ks)
#pragma unroll
            for (int fn = 0; fn < 4; ++fn) {
                const int row = fn * 16 + l15;
                int byte = (row << 7) + ((ks * 32 + l4 * 8) << 1);
                byte ^= (row & 7) << 4;
                const bf16x8 kf = *(const bf16x8*)(lK + byte);
#pragma unroll
                for (int fm = 0; fm < 2; ++fm)
                    sa[fm][fn] = __builtin_amdgcn_mfma_f32_16x16x32_bf16(
                        qa[fm][ks], kf, sa[fm][fn], 0, 0, 0);
            }

        // online softmax + P scatter (wave-private)
#pragma unroll
        for (int fm = 0; fm < 2; ++fm)
#pragma unroll
            for (int r = 0; r < 4; ++r) {
                float mx = fmaxf(fmaxf(sa[fm][0][r], sa[fm][1][r]),
                                 fmaxf(sa[fm][2][r], sa[fm][3][r]));
#pragma unroll
                for (int m_ = 1; m_ < 16; m_ <<= 1) mx = fmaxf(mx, __shfl_xor(mx, m_));
                const float nm = fmaxf(mrun[fm][r], mx);
                const float al = __expf(mrun[fm][r] - nm);
                mrun[fm][r] = nm;
                float p0 = __expf(sa[fm][0][r] - nm), p1 = __expf(sa[fm][1][r] - nm);
                float p2 = __expf(sa[fm][2][r] - nm), p3 = __expf(sa[fm][3][r] - nm);
                float ps = p0 + p1 + p2 + p3;
#pragma unroll
                for (int m_ = 1; m_ < 16; m_ <<= 1) ps += __shfl_xor(ps, m_);
                lrun[fm][r] = lrun[fm][r] * al + ps;
#pragma unroll
                for (int fn = 0; fn < 4; ++fn) O[fm][fn][r] *= al;
                const int row = fm * 16 + l4 * 4 + r;   // local 0..31
                const int rsw = (row & 7) << 4;
                const int rb_ = row << 7;
                *(u16*)(lP + ((rb_ + ((0 * 16 + l15) << 1)) ^ rsw)) = f2bu(p0);
                *(u16*)(lP + ((rb_ + ((1 * 16 + l15) << 1)) ^ rsw)) = f2bu(p1);
                *(u16*)(lP + ((rb_ + ((2 * 16 + l15) << 1)) ^ rsw)) = f2bu(p2);
                *(u16*)(lP + ((rb_ + ((3 * 16 + l15) << 1)) ^ rsw)) = f2bu(p3);
            }

        // PV
#pragma unroll
        for (int ks = 0; ks < 2; ++ks) {
            bf16x8 pa[2];
#pragma unroll
            for (int fm = 0; fm < 2; ++fm) {
                const int row = fm * 16 + l15;
                int pbyte = (row << 7) + ((ks * 32 + l4 * 8) << 1);
                pbyte ^= (row & 7) << 4;
                pa[fm] = *(const bf16x8*)(lP + pbyte);
            }
#pragma unroll
            for (int fn = 0; fn < 4; ++fn) {
                const int row = fn * 16 + l15;
                int byte = (row << 7) + ((ks * 32 + l4 * 8) << 1);
                byte ^= (row & 7) << 4;
                const bf16x8 vf = *(const bf16x8*)(lV + byte);
#pragma unroll
                for (int fm = 0; fm < 2; ++fm)
                    O[fm][fn] = __builtin_amdgcn_mfma_f32_16x16x32_bf16(
                        pa[fm], vf, O[fm][fn], 0, 0, 0);
            }
        }
    }

    // epilogue: h += O / l
#pragma unroll
    for (int fm = 0; fm < 2; ++fm) {
        float rinv[4];
#pragma unroll
        for (int r = 0; r < 4; ++r) rinv[r] = 1.0f / lrun[fm][r];
#pragma unroll
        for (int fn = 0; fn < 4; ++fn)
#pragma unroll
            for (int r = 0; r < 4; ++r) {
                const int qrow = q0 + wave * 32 + fm * 16 + l4 * 4 + r;
                const int e = fn * 16 + l15;
                h[((long)b * SEQ + qrow) * DMODEL + hd * HDIM + e] += O[fm][fn][r] * rinv[r];
            }
    }
}

// ---------------------------------------------------------------------------
// MLP GEMM1 (3-buffer pipelined, tiled B): ff1 = gelu(z @ w1t^T + b1).
// grid (8, 32), 512 threads. LDS 144KB.
// ---------------------------------------------------------------------------
__global__ __launch_bounds__(512, 1) void k_gemm1(const bf16* __restrict__ zb,
                                                  const bf16* __restrict__ w1t,
                                                  const float* __restrict__ b1,
                                                  bf16* __restrict__ ff1)
{
    __shared__ __align__(16) char lmem[147456];   // lA 3x32KB + lB 3x16KB
    const int bx = (int)blockIdx.y >> 2;
    const int by = (int)blockIdx.x * 4 + ((int)blockIdx.y & 3);
    const bf16* A = zb + (long)bx * 256 * DMODEL;
    const bf16* Bt = w1t + (long)by * 16 * 8192;
    f32x4 acc[8][2] = {};
    gemm_pipe(A, DMODEL, Bt, DMODEL / 64, acc, lmem, lmem + 98304);

    const int lane = threadIdx.x & 63, wave = threadIdx.x >> 6;
    const int wr = wave >> 2, wc = wave & 3;
    const int l15 = lane & 15, l4 = lane >> 4;
#pragma unroll
    for (int fm = 0; fm < 8; ++fm)
#pragma unroll
        for (int fn = 0; fn < 2; ++fn)
#pragma unroll
            for (int r = 0; r < 4; ++r) {
                const int row = bx * 256 + wr * 128 + fm * 16 + l4 * 4 + r;
                const int col = by * 128 + wc * 32 + fn * 16 + l15;
                const float x = acc[fm][fn][r] + b1[col];
                const float g = 0.5f * x * (1.0f + erff(x * 0.70710678118f));
                ff1[(long)row * FFDIM + col] = __float2bfloat16(g);
            }
}

// ---------------------------------------------------------------------------
// MLP GEMM2 (3-buffer pipelined, tiled B, split-K=4): part[sk] (bf16).
// grid (8, 8, 4), 512 threads.
// ---------------------------------------------------------------------------
__global__ __launch_bounds__(512, 1) void k_gemm2(const bf16* __restrict__ ff1,
                                                  const bf16* __restrict__ w2t,
                                                  bf16* __restrict__ part)
{
    __shared__ __align__(16) char lmem[147456];
    const int sk = blockIdx.z;
    const int bx = (int)blockIdx.y;
    const int by = (int)blockIdx.x;
    const bf16* A = ff1 + (long)bx * 256 * FFDIM + (long)sk * 1024;
    const bf16* Bt = w2t + ((long)by * 64 + sk * 16) * 8192;
    f32x4 acc[8][2] = {};
    gemm_pipe(A, FFDIM, Bt, 1024 / 64, acc, lmem, lmem + 98304);

    bf16* out = part + (long)sk * (NB * SEQ) * DMODEL;
    const int lane = threadIdx.x & 63, wave = threadIdx.x >> 6;
    const int wr = wave >> 2, wc = wave & 3;
    const int l15 = lane & 15, l4 = lane >> 4;
#pragma unroll
    for (int fm = 0; fm < 8; ++fm)
#pragma unroll
        for (int fn = 0; fn < 2; ++fn)
#pragma unroll
            for (int r = 0; r < 4; ++r) {
                const int row = bx * 256 + wr * 128 + fm * 16 + l4 * 4 + r;
                const int col = by * 128 + wc * 32 + fn * 16 + l15;
                out[(long)row * DMODEL + col] = __float2bfloat16(acc[fm][fn][r]);
            }
}

// ---------------------------------------------------------------------------
// Fused: h += sum_k part[k] (bf16) + b2, optional next-layer LN1.
// ---------------------------------------------------------------------------
__global__ __launch_bounds__(256) void k_red2ln(const bf16* __restrict__ part,
                                                const float* __restrict__ b2,
                                                float* __restrict__ h,
                                                const float* __restrict__ lnw,
                                                const float* __restrict__ lnb,
                                                bf16* __restrict__ y,
                                                int do_ln)
{
    constexpr long NELT = (long)NB * SEQ * DMODEL;
    const long row = blockIdx.x;
    const int tid = threadIdx.x;
    const long e0 = row * DMODEL + tid * 4;
    float sum[4] = {0.f, 0.f, 0.f, 0.f};
#pragma unroll
    for (int sk = 0; sk < 4; ++sk) {
        const uint2 u = *(const uint2*)(part + sk * NELT + e0);
        sum[0] += bu2f((u16)(u.x & 0xffffu));
        sum[1] += bu2f((u16)(u.x >> 16));
        sum[2] += bu2f((u16)(u.y & 0xffffu));
        sum[3] += bu2f((u16)(u.y >> 16));
    }
    const float4 bv = ((const float4*)b2)[tid];
    float4 hv = ((float4*)h)[row * (DMODEL / 4) + tid];
    hv.x += sum[0] + bv.x;
    hv.y += sum[1] + bv.y;
    hv.z += sum[2] + bv.z;
    hv.w += sum[3] + bv.w;
    ((float4*)h)[row * (DMODEL / 4) + tid] = hv;

    if (!do_ln) return;
    float ss  = hv.x + hv.y + hv.z + hv.w;
    float ss2 = hv.x * hv.x + hv.y * hv.y + hv.z * hv.z + hv.w * hv.w;
#pragma unroll
    for (int off = 32; off; off >>= 1) { ss += __shfl_xor(ss, off); ss2 += __shfl_xor(ss2, off); }
    __shared__ float rs[4], rs2[4];
    const int wave = tid >> 6;
    if ((tid & 63) == 0) { rs[wave] = ss; rs2[wave] = ss2; }
    __syncthreads();
    const float S1 = rs[0] + rs[1] + rs[2] + rs[3];
    const float S2 = rs2[0] + rs2[1] + rs2[2] + rs2[3];
    const float mean = S1 * (1.0f / DMODEL);
    const float var  = S2 * (1.0f / DMODEL) - mean * mean;
    const float rstd = rsqrtf(var + 1e-5f);
    const float4 wv = ((const float4*)lnw)[tid];
    const float4 lb = ((const float4*)lnb)[tid];
    uint2 o;
    o.x = (u32)f2bu((hv.x - mean) * rstd * wv.x + lb.x) |
          ((u32)f2bu((hv.y - mean) * rstd * wv.y + lb.y) << 16);
    o.y = (u32)f2bu((hv.z - mean) * rstd * wv.z + lb.z) |
          ((u32)f2bu((hv.w - mean) * rstd * wv.w + lb.w) << 16);
    ((uint2*)(y + row * DMODEL))[tid] = o;
}

// ---------------------------------------------------------------------------
extern "C" void kernel_launch(void* const* d_in, const int* in_sizes, int n_in,
                              void* d_out, int out_size, void* d_ws, size_t ws_size,
                              hipStream_t stream)
{
    const float* x    = (const float*)d_in[0];
    const float* ln1w = (const float*)d_in[1];
    const float* ln1b = (const float*)d_in[2];
    const float* qw   = (const float*)d_in[3];
    const float* qb   = (const float*)d_in[4];
    const float* kw   = (const float*)d_in[5];
    const float* kb   = (const float*)d_in[6];
    const float* vw   = (const float*)d_in[7];
    const float* vb   = (const float*)d_in[8];
    const float* ln2w = (const float*)d_in[9];
    const float* ln2b = (const float*)d_in[10];
    const float* w1   = (const float*)d_in[11];
    const float* b1   = (const float*)d_in[12];
    const float* w2   = (const float*)d_in[13];
    const float* b2   = (const float*)d_in[14];

    char* ws = (char*)d_ws;
    const size_t MB = 1024 * 1024;
    bf16* y    = (bf16*)(ws + 0 * MB);     // [2048,1024] bf16 : 4MB
    bf16* zb   = (bf16*)(ws + 4 * MB);     // [2048,1024] bf16 : 4MB
    bf16* ff1  = (bf16*)(ws + 20 * MB);    // [2048,4096]      : 16MB
    bf16* part = (bf16*)(ws + 36 * MB);    // [4,2048,1024] bf16: 16MB
    bf16* w1tA = (bf16*)(ws + 68 * MB);    // [8][32 panels][16 tiles][8192] : 64MB
    bf16* w2tA = (bf16*)(ws + 132 * MB);   // [8][8 panels][64 tiles][8192]  : 64MB

    float* h = (float*)d_out;

    // all-layer weight -> swizzled tiles, once
    k_tilew2<<<NLAYER * 256, 256, 0, stream>>>(w1, w2, w1tA, w2tA);
    // initial LN1 for layer 0 (reads x, also writes h = x)
    k_ln<<<NB * SEQ, 256, 0, stream>>>(x, ln1w, ln1b, y, h);

    for (int l = 0; l < NLAYER; ++l) {
        const long wofs = (long)l * DMODEL * FFDIM;
        k_attn<<<dim3(SEQ / 128, NB * NHEAD), 256, 0, stream>>>(
            y, qw + (long)l * 65536, kw + (long)l * 65536, vw + (long)l * 65536,
            qb + l * NHEAD * HDIM, kb + l * NHEAD * HDIM, vb + l * NHEAD * HDIM, h);
        k_ln<<<NB * SEQ, 256, 0, stream>>>(h, ln2w + l * DMODEL, ln2b + l * DMODEL, zb,
                                           nullptr);
        k_gemm1<<<dim3(8, 32), 512, 0, stream>>>(zb, w1tA + wofs, b1 + l * FFDIM, ff1);
        k_gemm2<<<dim3(8, 8, 4), 512, 0, stream>>>(ff1, w2tA + wofs, part);
        const int last = (l == NLAYER - 1);
        k_red2ln<<<NB * SEQ, 256, 0, stream>>>(part, b2 + l * DMODEL, h,
                                               ln1w + (l + 1) * DMODEL * (1 - last),
                                               ln1b + (l + 1) * DMODEL * (1 - last),
                                               y, !last);
    }
}

// Round 17
// 915.849 us; speedup vs baseline: 1.0113x; 1.0113x over previous
//
#include <hip/hip_runtime.h>
#include <hip/hip_bf16.h>

typedef __hip_bfloat16 bf16;
typedef __bf16 bf16x8 __attribute__((ext_vector_type(8)));
typedef float f32x4 __attribute__((ext_vector_type(4)));
typedef unsigned short u16;
typedef unsigned int u32;

#define SEQ 512
#define DMODEL 1024
#define FFDIM 4096
#define NHEAD 16
#define HDIM 64
#define NB 4
#define NLAYER 8

#define SBAR() asm volatile("s_barrier" ::: "memory")

__device__ __forceinline__ u16 f2bu(float f) {
    union { bf16 h; u16 u; } c; c.h = __float2bfloat16(f); return c.u;
}
__device__ __forceinline__ float bu2f(u16 u) {
    union { u32 i; float f; } c; c.i = ((u32)u) << 16; return c.f;
}

// async global->LDS, 16B per lane. LDS dest must be linear in lane order.
__device__ __forceinline__ void gload16(const bf16* g, bf16* l) {
    __builtin_amdgcn_global_load_lds(
        (const __attribute__((address_space(1))) unsigned int*)g,
        (__attribute__((address_space(3))) unsigned int*)l,
        16, 0, 0);
}

// ---------------------------------------------------------------------------
// Deep-pipelined NT GEMM core, 3-buffer LDS ring: 256x128 tile, BK=64,
// 512 threads (8 waves 2Mx4N). stage(t+2) issues into the FREE ring slot at
// iteration start (overlaps MFMA); counted vmcnt(6) waits only tile t+1's
// loads; ONE barrier per K-tile. A: row-major global w/ st_16x32 swizzle via
// inverse-swizzled source. B: tiled global layout (swizzle pre-baked).
// ---------------------------------------------------------------------------
__device__ __forceinline__ void gemm_pipe(
    const bf16* __restrict__ A, int lda,
    const bf16* __restrict__ Bt,       // tiled B: + t*8192 per K-tile
    int nkt,
    f32x4 (&acc)[8][2],
    char* lA, char* lB)                // lA: 3 x 32KB, lB: 3 x 16KB
{
    const int tid = threadIdx.x;
    const int lane = tid & 63;
    const int wave = tid >> 6;
    const int wr = wave >> 2, wc = wave & 3;
    const int l15 = lane & 15, l4 = lane >> 4;

    auto stage = [&](int c, int t) {
        const bf16* Ak = A + t * 64;
        bf16* dA = (bf16*)(lA + c * 32768);
        bf16* dB = (bf16*)(lB + c * 16384);
#pragma unroll
        for (int it = 0; it < 4; ++it) {
            const int e = (it * 512 + tid) * 8;
            const int r = e >> 6;
            const int cb = (e & 63) * 2;
            const int sc = (cb ^ (((r >> 2) & 1) << 5)) >> 1;
            gload16(Ak + (long)r * lda + sc, dA + e);
        }
        const bf16* Bk = Bt + (long)t * 8192;
#pragma unroll
        for (int it = 0; it < 2; ++it) {
            const int e = (it * 512 + tid) * 8;
            gload16(Bk + e, dB + e);
        }
    };

    stage(0, 0);
    stage(1, 1);
    asm volatile("s_waitcnt vmcnt(6)" ::: "memory");   // tile 0 resident
    SBAR();

    for (int t = 0; t < nkt; ++t) {
        const int cur = t % 3;
        // issue next-next tile into the free ring slot; flies under MFMA.
        if (t + 2 < nkt) stage((t + 2) % 3, t + 2);

        const char* bA = lA + cur * 32768;
        const char* bB = lB + cur * 16384;

        bf16x8 bf_[2][2];
#pragma unroll
        for (int fn = 0; fn < 2; ++fn)
#pragma unroll
            for (int ks = 0; ks < 2; ++ks) {
                const int row = wc * 32 + fn * 16 + l15;
                int byte = row * 128 + (ks * 32 + l4 * 8) * 2;
                byte ^= ((row >> 2) & 1) << 5;
                bf_[fn][ks] = *(const bf16x8*)(bB + byte);
            }
#pragma unroll
        for (int q = 0; q < 4; ++q) {
            bf16x8 af[2][2];
#pragma unroll
            for (int i = 0; i < 2; ++i)
#pragma unroll
                for (int ks = 0; ks < 2; ++ks) {
                    const int row = wr * 128 + (q * 2 + i) * 16 + l15;
                    int byte = row * 128 + (ks * 32 + l4 * 8) * 2;
                    byte ^= ((row >> 2) & 1) << 5;
                    af[i][ks] = *(const bf16x8*)(bA + byte);
                }
            __builtin_amdgcn_s_setprio(1);
#pragma unroll
            for (int i = 0; i < 2; ++i)
#pragma unroll
                for (int fn = 0; fn < 2; ++fn)
#pragma unroll
                    for (int ks = 0; ks < 2; ++ks)
                        acc[q * 2 + i][fn] = __builtin_amdgcn_mfma_f32_16x16x32_bf16(
                            af[i][ks], bf_[fn][ks], acc[q * 2 + i][fn], 0, 0, 0);
            __builtin_amdgcn_s_setprio(0);
        }
        // wait tile t+1 (oldest 6 outstanding); t+2's 6 stay in flight
        if (t + 2 < nkt) {
            asm volatile("s_waitcnt vmcnt(6)" ::: "memory");
        } else if (t + 1 < nkt) {
            asm volatile("s_waitcnt vmcnt(0)" ::: "memory");
        }
        SBAR();   // tile t+1 visible to all; all waves past buf[cur] reads
    }
}

// ---------------------------------------------------------------------------
// LayerNorm: in (fp32, row of 1024) -> out bf16; optional passthrough copy.
// ---------------------------------------------------------------------------
__global__ __launch_bounds__(256) void k_ln(const float* __restrict__ h,
                                            const float* __restrict__ w,
                                            const float* __restrict__ bp,
                                            bf16* __restrict__ out,
                                            float* __restrict__ hcopy)
{
    const int row = blockIdx.x;
    const int tid = threadIdx.x;
    const float4 x = ((const float4*)(h + (long)row * DMODEL))[tid];
    if (hcopy) ((float4*)(hcopy + (long)row * DMODEL))[tid] = x;
    float s  = x.x + x.y + x.z + x.w;
    float s2 = x.x * x.x + x.y * x.y + x.z * x.z + x.w * x.w;
#pragma unroll
    for (int off = 32; off; off >>= 1) { s += __shfl_xor(s, off); s2 += __shfl_xor(s2, off); }
    __shared__ float rs[4], rs2[4];
    const int wave = tid >> 6;
    if ((tid & 63) == 0) { rs[wave] = s; rs2[wave] = s2; }
    __syncthreads();
    const float S1 = rs[0] + rs[1] + rs[2] + rs[3];
    const float S2 = rs2[0] + rs2[1] + rs2[2] + rs2[3];
    const float mean = S1 * (1.0f / DMODEL);
    const float var  = S2 * (1.0f / DMODEL) - mean * mean;
    const float rstd = rsqrtf(var + 1e-5f);
    const float4 wv = ((const float4*)w)[tid];
    const float4 bv = ((const float4*)bp)[tid];
    uint2 o;
    o.x = (u32)f2bu((x.x - mean) * rstd * wv.x + bv.x) |
          ((u32)f2bu((x.y - mean) * rstd * wv.y + bv.y) << 16);
    o.y = (u32)f2bu((x.z - mean) * rstd * wv.z + bv.z) |
          ((u32)f2bu((x.w - mean) * rstd * wv.w + bv.w) << 16);
    ((uint2*)(out + (long)row * DMODEL))[tid] = o;
}

// ---------------------------------------------------------------------------
// Weight -> swizzled-tile converter (v1, best variant; memory-system-bound).
// ---------------------------------------------------------------------------
__global__ __launch_bounds__(256) void k_tilew(const float* __restrict__ w1,
                                               const float* __restrict__ w2,
                                               bf16* __restrict__ w1t,
                                               bf16* __restrict__ w2t)
{
    __shared__ u16 t[64][138];
    int bid = blockIdx.x;
    const int l = bid >> 10;
    bid &= 1023;
    const long lofs = (long)l * DMODEL * FFDIM;
    const float* src; bf16* dst; int ldsrc;
    if (bid < 512) {
        const int by = bid >> 4, kt = bid & 15;
        src = w1 + lofs + (long)(kt * 64) * FFDIM + by * 128;
        ldsrc = FFDIM;
        dst = w1t + lofs + ((long)by * 16 + kt) * 8192;
    } else {
        bid -= 512;
        const int by = bid >> 6, kt = bid & 63;
        src = w2 + lofs + (long)(kt * 64) * DMODEL + by * 128;
        ldsrc = DMODEL;
        dst = w2t + lofs + ((long)by * 64 + kt) * 8192;
    }
    const int tid = threadIdx.x;
    const int n4 = (tid & 31) * 4;
    const int kr = tid >> 5;
#pragma unroll
    for (int j = 0; j < 8; ++j) {
        const int k = j * 8 + kr;
        const float4 v = *(const float4*)(src + (long)k * ldsrc + n4);
        t[k][n4]     = f2bu(v.x);
        t[k][n4 + 1] = f2bu(v.y);
        t[k][n4 + 2] = f2bu(v.z);
        t[k][n4 + 3] = f2bu(v.w);
    }
    __syncthreads();
#pragma unroll
    for (int it = 0; it < 4; ++it) {
        const int e0 = it * 2048 + tid * 8;
        const int r = e0 >> 6;
        const int c = e0 & 63;
        const int ksw = c ^ (((r >> 2) & 1) << 4);
        u16 v[8];
#pragma unroll
        for (int m = 0; m < 8; ++m) v[m] = t[ksw + m][r];
        uint4 o;
        o.x = (u32)v[0] | ((u32)v[1] << 16);
        o.y = (u32)v[2] | ((u32)v[3] << 16);
        o.z = (u32)v[4] | ((u32)v[5] << 16);
        o.w = (u32)v[6] | ((u32)v[7] << 16);
        *(uint4*)(dst + e0) = o;
    }
}

// ---------------------------------------------------------------------------
// Fused QKV + flash attention. grid (SEQ/128=4, B*H=64), 256 threads (4 waves,
// 32 q-rows each). Per block: stage Wq/Wk/Wv (fp32->bf16) + q-tile y-rows;
// project Q once; per kv-tile generate K,V via MFMA (bias fused, V stored
// transposed in LDS) then QK^T -> online softmax -> PV. h += O/l.
// ---------------------------------------------------------------------------
__global__ __launch_bounds__(256) void k_attn(const bf16* __restrict__ y,
                                              const float* __restrict__ qwl,
                                              const float* __restrict__ kwl,
                                              const float* __restrict__ vwl,
                                              const float* __restrict__ qb,
                                              const float* __restrict__ kb,
                                              const float* __restrict__ vb,
                                              float* __restrict__ h)
{
    __shared__ __align__(16) char lmem[65536];
    bf16* lY  = (bf16*)lmem;            // 16KB: y staging (A-swizzled)
    char* lQ  = lmem + 16384;           // 16KB: Q scatter; later per-wave P
    char* lK  = lmem + 32768;           // 8KB: Wq temp, then K tile
    char* lV  = lmem + 40960;           // 8KB: V tile (transposed)
    char* lWk = lmem + 49152;           // 8KB
    char* lWv = lmem + 57344;           // 8KB

    const int tid = threadIdx.x;
    const int lane = tid & 63, wave = tid >> 6;
    const int l15 = lane & 15, l4 = lane >> 4;
    const int z = blockIdx.y, b = z >> 4, hd = z & 15;
    const int q0 = blockIdx.x * 128;

    // stage Wq->lK(temp), Wk->lWk, Wv->lWv : fp32->bf16 + row swizzle
    {
        const float* s0 = qwl + (long)hd * HDIM * HDIM;
        const float* s1 = kwl + (long)hd * HDIM * HDIM;
        const float* s2 = vwl + (long)hd * HDIM * HDIM;
#pragma unroll
        for (int it = 0; it < 4; ++it) {
            const int f = (it * 256 + tid) * 4;
            const int row = f >> 6;
            const int byte = (f << 1) ^ ((row & 7) << 4);
            float4 v = *(const float4*)(s0 + f);
            uint2 o;
            o.x = (u32)f2bu(v.x) | ((u32)f2bu(v.y) << 16);
            o.y = (u32)f2bu(v.z) | ((u32)f2bu(v.w) << 16);
            *(uint2*)(lK + byte) = o;
            v = *(const float4*)(s1 + f);
            o.x = (u32)f2bu(v.x) | ((u32)f2bu(v.y) << 16);
            o.y = (u32)f2bu(v.z) | ((u32)f2bu(v.w) << 16);
            *(uint2*)(lWk + byte) = o;
            v = *(const float4*)(s2 + f);
            o.x = (u32)f2bu(v.x) | ((u32)f2bu(v.y) << 16);
            o.y = (u32)f2bu(v.z) | ((u32)f2bu(v.w) << 16);
            *(uint2*)(lWv + byte) = o;
        }
    }
    // stage y_q (128 rows) -> lY with inverse-swizzled source
    const bf16* Yq = y + ((long)b * SEQ + q0) * DMODEL + hd * HDIM;
#pragma unroll
    for (int it = 0; it < 4; ++it) {
        const int e = (it * 256 + tid) * 8;
        const int r = e >> 6;
        const int cb = (e & 63) * 2;
        const int sc = (cb ^ (((r >> 2) & 1) << 5)) >> 1;
        gload16(Yq + (long)r * DMODEL + sc, lY + e);
    }
    __syncthreads();

    // Q projection: per wave 32 rows; scatter to lQ (C-layout, row-swizzled)
    {
        f32x4 qacc[2][4] = {};
#pragma unroll
        for (int ks = 0; ks < 2; ++ks) {
            bf16x8 af[2];
#pragma unroll
            for (int fm = 0; fm < 2; ++fm) {
                const int row = wave * 32 + fm * 16 + l15;
                int byte = row * 128 + (ks * 32 + l4 * 8) * 2;
                byte ^= ((row >> 2) & 1) << 5;
                af[fm] = *(const bf16x8*)((char*)lY + byte);
            }
#pragma unroll
            for (int fn = 0; fn < 4; ++fn) {
                const int wrow = fn * 16 + l15;
                int wbyte = (wrow << 7) + ((ks * 32 + l4 * 8) << 1);
                wbyte ^= (wrow & 7) << 4;
                const bf16x8 wf = *(const bf16x8*)(lK + wbyte);
#pragma unroll
                for (int fm = 0; fm < 2; ++fm)
                    qacc[fm][fn] = __builtin_amdgcn_mfma_f32_16x16x32_bf16(
                        af[fm], wf, qacc[fm][fn], 0, 0, 0);
            }
        }
#pragma unroll
        for (int fm = 0; fm < 2; ++fm)
#pragma unroll
            for (int fn = 0; fn < 4; ++fn) {
                const int e = fn * 16 + l15;
                const float bias = qb[hd * HDIM + e];
#pragma unroll
                for (int r = 0; r < 4; ++r) {
                    const int row = wave * 32 + fm * 16 + l4 * 4 + r;
                    const int byte = ((row << 7) + (e << 1)) ^ ((row & 7) << 4);
                    *(u16*)(lQ + byte) = f2bu((qacc[fm][fn][r] + bias) * 0.125f);
                }
            }
    }
    __syncthreads();

    // qa readback (A-layout)
    bf16x8 qa[2][2];
#pragma unroll
    for (int fm = 0; fm < 2; ++fm)
#pragma unroll
        for (int ks = 0; ks < 2; ++ks) {
            const int row = wave * 32 + fm * 16 + l15;
            int byte = (row << 7) + ((ks * 32 + l4 * 8) << 1);
            byte ^= (row & 7) << 4;
            qa[fm][ks] = *(const bf16x8*)(lQ + byte);
        }

    char* lP = lQ + wave * 4096;   // wave-private 32x64 P (aliases own Q rows)

    f32x4 O[2][4] = {};
    float mrun[2][4], lrun[2][4];
#pragma unroll
    for (int fm = 0; fm < 2; ++fm)
#pragma unroll
        for (int r = 0; r < 4; ++r) { mrun[fm][r] = -1e30f; lrun[fm][r] = 0.0f; }

    for (int kv = 0; kv < SEQ / 64; ++kv) {
        __syncthreads();   // prior tile's lY/lK/lV readers done
        const bf16* Ykv = y + ((long)b * SEQ + kv * 64) * DMODEL + hd * HDIM;
#pragma unroll
        for (int it = 0; it < 2; ++it) {
            const int e = (it * 256 + tid) * 8;
            const int r = e >> 6;
            const int cb = (e & 63) * 2;
            const int sc = (cb ^ (((r >> 2) & 1) << 5)) >> 1;
            gload16(Ykv + (long)r * DMODEL + sc, lY + e);
        }
        __syncthreads();   // y_kv ready (vmcnt drained)

        // K,V generation: wave owns keys [wave*16, wave*16+16)
        {
            f32x4 kacc[4] = {}, vacc[4] = {};
#pragma unroll
            for (int ks = 0; ks < 2; ++ks) {
                const int yrow = wave * 16 + l15;
                int ybyte = yrow * 128 + (ks * 32 + l4 * 8) * 2;
                ybyte ^= ((yrow >> 2) & 1) << 5;
                const bf16x8 ay = *(const bf16x8*)((char*)lY + ybyte);
#pragma unroll
                for (int fn = 0; fn < 4; ++fn) {
                    const int wrow = fn * 16 + l15;
                    int wbyte = (wrow << 7) + ((ks * 32 + l4 * 8) << 1);
                    wbyte ^= (wrow & 7) << 4;
                    kacc[fn] = __builtin_amdgcn_mfma_f32_16x16x32_bf16(
                        ay, *(const bf16x8*)(lWk + wbyte), kacc[fn], 0, 0, 0);
                    vacc[fn] = __builtin_amdgcn_mfma_f32_16x16x32_bf16(
                        ay, *(const bf16x8*)(lWv + wbyte), vacc[fn], 0, 0, 0);
                }
            }
#pragma unroll
            for (int fn = 0; fn < 4; ++fn) {
                const int e = fn * 16 + l15;
                const float kbv = kb[hd * HDIM + e];
                const float vbv = vb[hd * HDIM + e];
#pragma unroll
                for (int r = 0; r < 4; ++r) {
                    const int key = wave * 16 + l4 * 4 + r;
                    const int kbyte = ((key << 7) + (e << 1)) ^ ((key & 7) << 4);
                    *(u16*)(lK + kbyte) = f2bu(kacc[fn][r] + kbv);
                    const int vbyte = ((e << 7) + (key << 1)) ^ ((e & 7) << 4);
                    *(u16*)(lV + vbyte) = f2bu(vacc[fn][r] + vbv);
                }
            }
        }
        __syncthreads();   // K/V tiles ready

        // QK^T
        f32x4 sa[2][4];
#pragma unroll
        for (int fm = 0; fm < 2; ++fm)
#pragma unroll
            for (int fn = 0; fn < 4; ++fn) sa[fm][fn] = (f32x4){0.f, 0.f, 0.f, 0.f};
#pragma unroll
        for (int ks = 0; ks < 2; ++ks)
#pragma unroll
            for (int fn = 0; fn < 4; ++fn) {
                const int row = fn * 16 + l15;
                int byte = (row << 7) + ((ks * 32 + l4 * 8) << 1);
                byte ^= (row & 7) << 4;
                const bf16x8 kf = *(const bf16x8*)(lK + byte);
#pragma unroll
                for (int fm = 0; fm < 2; ++fm)
                    sa[fm][fn] = __builtin_amdgcn_mfma_f32_16x16x32_bf16(
                        qa[fm][ks], kf, sa[fm][fn], 0, 0, 0);
            }

        // online softmax + P scatter (wave-private)
#pragma unroll
        for (int fm = 0; fm < 2; ++fm)
#pragma unroll
            for (int r = 0; r < 4; ++r) {
                float mx = fmaxf(fmaxf(sa[fm][0][r], sa[fm][1][r]),
                                 fmaxf(sa[fm][2][r], sa[fm][3][r]));
#pragma unroll
                for (int m_ = 1; m_ < 16; m_ <<= 1) mx = fmaxf(mx, __shfl_xor(mx, m_));
                const float nm = fmaxf(mrun[fm][r], mx);
                const float al = __expf(mrun[fm][r] - nm);
                mrun[fm][r] = nm;
                float p0 = __expf(sa[fm][0][r] - nm), p1 = __expf(sa[fm][1][r] - nm);
                float p2 = __expf(sa[fm][2][r] - nm), p3 = __expf(sa[fm][3][r] - nm);
                float ps = p0 + p1 + p2 + p3;
#pragma unroll
                for (int m_ = 1; m_ < 16; m_ <<= 1) ps += __shfl_xor(ps, m_);
                lrun[fm][r] = lrun[fm][r] * al + ps;
#pragma unroll
                for (int fn = 0; fn < 4; ++fn) O[fm][fn][r] *= al;
                const int row = fm * 16 + l4 * 4 + r;   // local 0..31
                const int rsw = (row & 7) << 4;
                const int rb_ = row << 7;
                *(u16*)(lP + ((rb_ + ((0 * 16 + l15) << 1)) ^ rsw)) = f2bu(p0);
                *(u16*)(lP + ((rb_ + ((1 * 16 + l15) << 1)) ^ rsw)) = f2bu(p1);
                *(u16*)(lP + ((rb_ + ((2 * 16 + l15) << 1)) ^ rsw)) = f2bu(p2);
                *(u16*)(lP + ((rb_ + ((3 * 16 + l15) << 1)) ^ rsw)) = f2bu(p3);
            }

        // PV
#pragma unroll
        for (int ks = 0; ks < 2; ++ks) {
            bf16x8 pa[2];
#pragma unroll
            for (int fm = 0; fm < 2; ++fm) {
                const int row = fm * 16 + l15;
                int pbyte = (row << 7) + ((ks * 32 + l4 * 8) << 1);
                pbyte ^= (row & 7) << 4;
                pa[fm] = *(const bf16x8*)(lP + pbyte);
            }
#pragma unroll
            for (int fn = 0; fn < 4; ++fn) {
                const int row = fn * 16 + l15;
                int byte = (row << 7) + ((ks * 32 + l4 * 8) << 1);
                byte ^= (row & 7) << 4;
                const bf16x8 vf = *(const bf16x8*)(lV + byte);
#pragma unroll
                for (int fm = 0; fm < 2; ++fm)
                    O[fm][fn] = __builtin_amdgcn_mfma_f32_16x16x32_bf16(
                        pa[fm], vf, O[fm][fn], 0, 0, 0);
            }
        }
    }

    // epilogue: h += O / l
#pragma unroll
    for (int fm = 0; fm < 2; ++fm) {
        float rinv[4];
#pragma unroll
        for (int r = 0; r < 4; ++r) rinv[r] = 1.0f / lrun[fm][r];
#pragma unroll
        for (int fn = 0; fn < 4; ++fn)
#pragma unroll
            for (int r = 0; r < 4; ++r) {
                const int qrow = q0 + wave * 32 + fm * 16 + l4 * 4 + r;
                const int e = fn * 16 + l15;
                h[((long)b * SEQ + qrow) * DMODEL + hd * HDIM + e] += O[fm][fn][r] * rinv[r];
            }
    }
}

// ---------------------------------------------------------------------------
// MLP GEMM1 (3-buffer pipelined, tiled B): ff1 = gelu(z @ w1t^T + b1).
// grid (8, 32), 512 threads. LDS 144KB.
// ---------------------------------------------------------------------------
__global__ __launch_bounds__(512, 1) void k_gemm1(const bf16* __restrict__ zb,
                                                  const bf16* __restrict__ w1t,
                                                  const float* __restrict__ b1,
                                                  bf16* __restrict__ ff1)
{
    __shared__ __align__(16) char lmem[147456];   // lA 3x32KB + lB 3x16KB
    const int bx = (int)blockIdx.y >> 2;
    const int by = (int)blockIdx.x * 4 + ((int)blockIdx.y & 3);
    const bf16* A = zb + (long)bx * 256 * DMODEL;
    const bf16* Bt = w1t + (long)by * 16 * 8192;
    f32x4 acc[8][2] = {};
    gemm_pipe(A, DMODEL, Bt, DMODEL / 64, acc, lmem, lmem + 98304);

    const int lane = threadIdx.x & 63, wave = threadIdx.x >> 6;
    const int wr = wave >> 2, wc = wave & 3;
    const int l15 = lane & 15, l4 = lane >> 4;
#pragma unroll
    for (int fm = 0; fm < 8; ++fm)
#pragma unroll
        for (int fn = 0; fn < 2; ++fn)
#pragma unroll
            for (int r = 0; r < 4; ++r) {
                const int row = bx * 256 + wr * 128 + fm * 16 + l4 * 4 + r;
                const int col = by * 128 + wc * 32 + fn * 16 + l15;
                const float x = acc[fm][fn][r] + b1[col];
                const float g = 0.5f * x * (1.0f + erff(x * 0.70710678118f));
                ff1[(long)row * FFDIM + col] = __float2bfloat16(g);
            }
}

// ---------------------------------------------------------------------------
// MLP GEMM2 (3-buffer pipelined, tiled B, split-K=4): part[sk] (bf16).
// grid (8, 8, 4), 512 threads.
// ---------------------------------------------------------------------------
__global__ __launch_bounds__(512, 1) void k_gemm2(const bf16* __restrict__ ff1,
                                                  const bf16* __restrict__ w2t,
                                                  bf16* __restrict__ part)
{
    __shared__ __align__(16) char lmem[147456];
    const int sk = blockIdx.z;
    const int bx = (int)blockIdx.y;
    const int by = (int)blockIdx.x;
    const bf16* A = ff1 + (long)bx * 256 * FFDIM + (long)sk * 1024;
    const bf16* Bt = w2t + ((long)by * 64 + sk * 16) * 8192;
    f32x4 acc[8][2] = {};
    gemm_pipe(A, FFDIM, Bt, 1024 / 64, acc, lmem, lmem + 98304);

    bf16* out = part + (long)sk * (NB * SEQ) * DMODEL;
    const int lane = threadIdx.x & 63, wave = threadIdx.x >> 6;
    const int wr = wave >> 2, wc = wave & 3;
    const int l15 = lane & 15, l4 = lane >> 4;
#pragma unroll
    for (int fm = 0; fm < 8; ++fm)
#pragma unroll
        for (int fn = 0; fn < 2; ++fn)
#pragma unroll
            for (int r = 0; r < 4; ++r) {
                const int row = bx * 256 + wr * 128 + fm * 16 + l4 * 4 + r;
                const int col = by * 128 + wc * 32 + fn * 16 + l15;
                out[(long)row * DMODEL + col] = __float2bfloat16(acc[fm][fn][r]);
            }
}

// ---------------------------------------------------------------------------
// Fused: h += sum_k part[k] (bf16) + b2, optional next-layer LN1.
// ---------------------------------------------------------------------------
__global__ __launch_bounds__(256) void k_red2ln(const bf16* __restrict__ part,
                                                const float* __restrict__ b2,
                                                float* __restrict__ h,
                                                const float* __restrict__ lnw,
                                                const float* __restrict__ lnb,
                                                bf16* __restrict__ y,
                                                int do_ln)
{
    constexpr long NELT = (long)NB * SEQ * DMODEL;
    const long row = blockIdx.x;
    const int tid = threadIdx.x;
    const long e0 = row * DMODEL + tid * 4;
    float sum[4] = {0.f, 0.f, 0.f, 0.f};
#pragma unroll
    for (int sk = 0; sk < 4; ++sk) {
        const uint2 u = *(const uint2*)(part + sk * NELT + e0);
        sum[0] += bu2f((u16)(u.x & 0xffffu));
        sum[1] += bu2f((u16)(u.x >> 16));
        sum[2] += bu2f((u16)(u.y & 0xffffu));
        sum[3] += bu2f((u16)(u.y >> 16));
    }
    const float4 bv = ((const float4*)b2)[tid];
    float4 hv = ((float4*)h)[row * (DMODEL / 4) + tid];
    hv.x += sum[0] + bv.x;
    hv.y += sum[1] + bv.y;
    hv.z += sum[2] + bv.z;
    hv.w += sum[3] + bv.w;
    ((float4*)h)[row * (DMODEL / 4) + tid] = hv;

    if (!do_ln) return;
    float ss  = hv.x + hv.y + hv.z + hv.w;
    float ss2 = hv.x * hv.x + hv.y * hv.y + hv.z * hv.z + hv.w * hv.w;
#pragma unroll
    for (int off = 32; off; off >>= 1) { ss += __shfl_xor(ss, off); ss2 += __shfl_xor(ss2, off); }
    __shared__ float rs[4], rs2[4];
    const int wave = tid >> 6;
    if ((tid & 63) == 0) { rs[wave] = ss; rs2[wave] = ss2; }
    __syncthreads();
    const float S1 = rs[0] + rs[1] + rs[2] + rs[3];
    const float S2 = rs2[0] + rs2[1] + rs2[2] + rs2[3];
    const float mean = S1 * (1.0f / DMODEL);
    const float var  = S2 * (1.0f / DMODEL) - mean * mean;
    const float rstd = rsqrtf(var + 1e-5f);
    const float4 wv = ((const float4*)lnw)[tid];
    const float4 lb = ((const float4*)lnb)[tid];
    uint2 o;
    o.x = (u32)f2bu((hv.x - mean) * rstd * wv.x + lb.x) |
          ((u32)f2bu((hv.y - mean) * rstd * wv.y + lb.y) << 16);
    o.y = (u32)f2bu((hv.z - mean) * rstd * wv.z + lb.z) |
          ((u32)f2bu((hv.w - mean) * rstd * wv.w + lb.w) << 16);
    ((uint2*)(y + row * DMODEL))[tid] = o;
}

// ---------------------------------------------------------------------------
extern "C" void kernel_launch(void* const* d_in, const int* in_sizes, int n_in,
                              void* d_out, int out_size, void* d_ws, size_t ws_size,
                              hipStream_t stream)
{
    const float* x    = (const float*)d_in[0];
    const float* ln1w = (const float*)d_in[1];
    const float* ln1b = (const float*)d_in[2];
    const float* qw   = (const float*)d_in[3];
    const float* qb   = (const float*)d_in[4];
    const float* kw   = (const float*)d_in[5];
    const float* kb   = (const float*)d_in[6];
    const float* vw   = (const float*)d_in[7];
    const float* vb   = (const float*)d_in[8];
    const float* ln2w = (const float*)d_in[9];
    const float* ln2b = (const float*)d_in[10];
    const float* w1   = (const float*)d_in[11];
    const float* b1   = (const float*)d_in[12];
    const float* w2   = (const float*)d_in[13];
    const float* b2   = (const float*)d_in[14];

    char* ws = (char*)d_ws;
    const size_t MB = 1024 * 1024;
    bf16* y    = (bf16*)(ws + 0 * MB);     // [2048,1024] bf16 : 4MB
    bf16* zb   = (bf16*)(ws + 4 * MB);     // [2048,1024] bf16 : 4MB
    bf16* ff1  = (bf16*)(ws + 20 * MB);    // [2048,4096]      : 16MB
    bf16* part = (bf16*)(ws + 36 * MB);    // [4,2048,1024] bf16: 16MB
    bf16* w1tA = (bf16*)(ws + 68 * MB);    // [8][32 panels][16 tiles][8192] : 64MB
    bf16* w2tA = (bf16*)(ws + 132 * MB);   // [8][8 panels][64 tiles][8192]  : 64MB

    float* h = (float*)d_out;

    // all-layer weight -> swizzled tiles, once
    k_tilew<<<NLAYER * 1024, 256, 0, stream>>>(w1, w2, w1tA, w2tA);
    // initial LN1 for layer 0 (reads x, also writes h = x)
    k_ln<<<NB * SEQ, 256, 0, stream>>>(x, ln1w, ln1b, y, h);

    for (int l = 0; l < NLAYER; ++l) {
        const long wofs = (long)l * DMODEL * FFDIM;
        k_attn<<<dim3(SEQ / 128, NB * NHEAD), 256, 0, stream>>>(
            y, qw + (long)l * 65536, kw + (long)l * 65536, vw + (long)l * 65536,
            qb + l * NHEAD * HDIM, kb + l * NHEAD * HDIM, vb + l * NHEAD * HDIM, h);
        k_ln<<<NB * SEQ, 256, 0, stream>>>(h, ln2w + l * DMODEL, ln2b + l * DMODEL, zb,
                                           nullptr);
        k_gemm1<<<dim3(8, 32), 512, 0, stream>>>(zb, w1tA + wofs, b1 + l * FFDIM, ff1);
        k_gemm2<<<dim3(8, 8, 4), 512, 0, stream>>>(ff1, w2tA + wofs, part);
        const int last = (l == NLAYER - 1);
        k_red2ln<<<NB * SEQ, 256, 0, stream>>>(part, b2 + l * DMODEL, h,
                                               ln1w + (l + 1) * DMODEL * (1 - last),
                                               ln1b + (l + 1) * DMODEL * (1 - last),
                                               y, !last);
    }
}